// Round 1
// baseline (375.004 us; speedup 1.0000x reference)
//
#include <hip/hip_runtime.h>
#include <math.h>

// Problem constants
#define B_    32
#define C_    256      // = D (embedding dim)
#define H_    32
#define W_    32
#define K_    1024     // num embeddings
#define N_    32768    // B*H*W pixels
#define NELEM 8388608  // B*C*H*W

// d_out layout (floats, concatenated in reference return order)
#define Q_OFF    1
#define PERP_OFF 8388609
#define IDX_OFF  8388610

// ws layout (bytes)
#define WS_COUNTS 0        // 1024 u32
#define WS_SUMSQ  4096     // 1 double
#define WS_EN2    8192     // 1024 f32
#define WS_XN2    12288    // 32768 f32
#define WS_IDX    143360   // 32768 i32

// ---------------------------------------------------------------------------
// K0: codebook row squared norms (f64 accumulate, round once to f32)
__global__ __launch_bounds__(256) void k_en2(const float* __restrict__ cb,
                                             float* __restrict__ en2) {
    int k = blockIdx.x * 256 + threadIdx.x;
    const float* row = cb + k * 256;
    double s = 0.0;
    for (int d = 0; d < 256; ++d) { double v = row[d]; s += v * v; }
    en2[k] = (float)s;
}

// K0b: per-pixel squared norms of x (NCHW, c-strided but lane-coalesced)
__global__ __launch_bounds__(256) void k_xn2(const float* __restrict__ x,
                                             float* __restrict__ xn2) {
    int n = blockIdx.x * 256 + threadIdx.x;
    int b = n >> 10, hw = n & 1023;
    const float* xp = x + b * 262144 + hw;
    double s = 0.0;
    for (int c = 0; c < 256; ++c) { double v = xp[c * 1024]; s += v * v; }
    xn2[n] = (float)s;
}

// ---------------------------------------------------------------------------
// K1: fused dot-products + argmin + histogram.
// Block: 256 threads = 16 ti (pixel groups of 4) x 16 tj (code groups of 8).
// Tile: 64 pixels x 128 codes per ktile, D chunked by 64 through LDS.
// LDS layouts are d-major: xs[d][p] (stride 64), es[d][k] (stride 132).
__global__ __launch_bounds__(256) void k_argmin(
    const float* __restrict__ x, const float* __restrict__ cb,
    const float* __restrict__ en2, const float* __restrict__ xn2,
    int* __restrict__ idx_out, float* __restrict__ idx_f,
    unsigned* __restrict__ counts) {
    __shared__ __align__(16) float xs[64 * 64];    // 16 KB
    __shared__ __align__(16) float es[64 * 132];   // 33 KB (pad breaks bank aliasing)

    const int t   = threadIdx.x;
    const int bid = blockIdx.x;
    const int b   = bid >> 4;             // 16 blocks per batch image
    const int hw0 = (bid & 15) << 6;      // 64 contiguous (h,w) pixels
    const float* xb = x + b * 262144 + hw0;
    const int ti = t >> 4, tj = t & 15;

    float xnr[4];
#pragma unroll
    for (int r = 0; r < 4; ++r) xnr[r] = xn2[(bid << 6) + (ti << 2) + r];

    float best_s[4];
    int   best_k[4];
#pragma unroll
    for (int r = 0; r < 4; ++r) { best_s[r] = INFINITY; best_k[r] = 0; }

    for (int kt = 0; kt < 8; ++kt) {
        float acc[4][8];
#pragma unroll
        for (int r = 0; r < 4; ++r)
#pragma unroll
            for (int j = 0; j < 8; ++j) acc[r][j] = 0.f;

        for (int dc = 0; dc < 4; ++dc) {
            __syncthreads();  // protect LDS from previous iteration's readers
            // stage x chunk: global is already [c][p]-contiguous -> direct f4
#pragma unroll
            for (int i = 0; i < 4; ++i) {
                int jv = (i << 8) + t;
                int c  = jv >> 4;
                int p4 = (jv & 15) << 2;
                const float4 v =
                    *(const float4*)(xb + ((dc << 6) + c) * 1024 + p4);
                *(float4*)(&xs[(c << 6) + p4]) = v;
            }
            // stage e chunk transposed: cb[k][d] -> es[d][k]
#pragma unroll
            for (int i = 0; i < 8; ++i) {
                int jv = (i << 8) + t;
                int k  = jv >> 4;
                int d4 = (jv & 15) << 2;
                const float4 v =
                    *(const float4*)(cb + ((kt << 7) + k) * 256 + (dc << 6) + d4);
                es[(d4 + 0) * 132 + k] = v.x;
                es[(d4 + 1) * 132 + k] = v.y;
                es[(d4 + 2) * 132 + k] = v.z;
                es[(d4 + 3) * 132 + k] = v.w;
            }
            __syncthreads();
#pragma unroll 4
            for (int d = 0; d < 64; ++d) {
                const float4 xv = *(const float4*)(&xs[(d << 6) + (ti << 2)]);
                const float4 e0 = *(const float4*)(&es[d * 132 + (tj << 3)]);
                const float4 e1 = *(const float4*)(&es[d * 132 + (tj << 3) + 4]);
                const float xr[4] = {xv.x, xv.y, xv.z, xv.w};
                const float ej[8] = {e0.x, e0.y, e0.z, e0.w,
                                     e1.x, e1.y, e1.z, e1.w};
#pragma unroll
                for (int r = 0; r < 4; ++r)
#pragma unroll
                    for (int j = 0; j < 8; ++j)
                        acc[r][j] = fmaf(xr[r], ej[j], acc[r][j]);
            }
        }
        // finalize this ktile: d = RN( RN(xn + en_k) - 2*dot ), ties -> smaller k
#pragma unroll
        for (int j = 0; j < 8; ++j) {
            const int   k  = (kt << 7) + (tj << 3) + j;
            const float en = en2[k];
#pragma unroll
            for (int r = 0; r < 4; ++r) {
                const float s1   = xnr[r] + en;
                const float dist = fmaf(-2.f, acc[r][j], s1);
                if (dist < best_s[r] || (dist == best_s[r] && k < best_k[r])) {
                    best_s[r] = dist;
                    best_k[r] = k;
                }
            }
        }
    }
    // reduce across the 16 tj lanes sharing each pixel (xor masks stay in-group)
#pragma unroll
    for (int r = 0; r < 4; ++r) {
        float s = best_s[r];
        int   k = best_k[r];
        for (int m = 1; m < 16; m <<= 1) {
            const float s2 = __shfl_xor(s, m, 64);
            const int   k2 = __shfl_xor(k, m, 64);
            if (s2 < s || (s2 == s && k2 < k)) { s = s2; k = k2; }
        }
        if (tj == 0) {
            const int n = (bid << 6) + (ti << 2) + r;
            idx_out[n] = k;
            idx_f[n]   = (float)k;
            atomicAdd(&counts[k], 1u);
        }
    }
}

// ---------------------------------------------------------------------------
// K2: gather codebook rows -> q_out (NCHW) + direct (q-x)^2 accumulation.
// Block handles one (b,h): 32 pixels x 256 channels.
__global__ __launch_bounds__(256) void k_gather(
    const float* __restrict__ x, const float* __restrict__ cb,
    const int* __restrict__ idxv, float* __restrict__ out,
    double* __restrict__ sumsq) {
    __shared__ __align__(16) float cs[32 * 260];  // [w][c], padded rows
    __shared__ int   kidx[32];
    __shared__ float wpart[4];

    const int t = threadIdx.x, bid = blockIdx.x;
    const int n0 = bid * 32;
    if (t < 32) kidx[t] = idxv[n0 + t];
    __syncthreads();
    // stage 32 codebook rows; one wave loads one full row (1 KB contiguous)
#pragma unroll
    for (int i = 0; i < 8; ++i) {
        int jv = (i << 8) + t;
        int p  = jv >> 6;
        int c4 = (jv & 63) << 2;
        const float4 v = *(const float4*)(cb + kidx[p] * 256 + c4);
        *(float4*)(&cs[p * 260 + c4]) = v;
    }
    __syncthreads();

    const int b = bid >> 5, h = bid & 31;
    const float* xb = x + b * 262144 + h * 32;
    float* qb = out + Q_OFF + b * 262144 + h * 32;  // 4B-aligned only -> scalar stores

    float local = 0.f;
#pragma unroll
    for (int i = 0; i < 8; ++i) {
        int j  = (i << 8) + t;
        int c  = j >> 3;
        int w4 = (j & 7) << 2;
        const float q0 = cs[(w4 + 0) * 260 + c];
        const float q1 = cs[(w4 + 1) * 260 + c];
        const float q2 = cs[(w4 + 2) * 260 + c];
        const float q3 = cs[(w4 + 3) * 260 + c];
        const float4 xv = *(const float4*)(xb + c * 1024 + w4);
        const float d0 = q0 - xv.x, d1 = q1 - xv.y;
        const float d2 = q2 - xv.z, d3 = q3 - xv.w;
        local += d0 * d0 + d1 * d1 + d2 * d2 + d3 * d3;
        qb[c * 1024 + w4 + 0] = q0;
        qb[c * 1024 + w4 + 1] = q1;
        qb[c * 1024 + w4 + 2] = q2;
        qb[c * 1024 + w4 + 3] = q3;
    }
    // block reduce -> one f64 atomic
    for (int m = 32; m > 0; m >>= 1) local += __shfl_down(local, m, 64);
    if ((t & 63) == 0) wpart[t >> 6] = local;
    __syncthreads();
    if (t == 0) {
        const float bs = wpart[0] + wpart[1] + wpart[2] + wpart[3];
        atomicAdd(sumsq, (double)bs);
    }
}

// ---------------------------------------------------------------------------
// K3: loss + perplexity finalize (single block)
__global__ __launch_bounds__(256) void k_final(const unsigned* __restrict__ counts,
                                               const double* __restrict__ sumsq,
                                               float* __restrict__ out) {
    __shared__ double part[256];
    const int t = threadIdx.x;
    double s = 0.0;
    for (int k = t; k < K_; k += 256) {
        const double p = (double)counts[k] / (double)N_;
        s += p * log(p + 1e-10);
    }
    part[t] = s;
    __syncthreads();
    for (int off = 128; off > 0; off >>= 1) {
        if (t < off) part[t] += part[t + off];
        __syncthreads();
    }
    if (t == 0) {
        out[PERP_OFF] = (float)exp(-part[0]);
        // q_latent_loss == e_latent_loss numerically -> (1 + 0.25) * mean
        out[0] = (float)(sumsq[0] * 1.25 / (double)NELEM);
    }
}

// ---------------------------------------------------------------------------
extern "C" void kernel_launch(void* const* d_in, const int* in_sizes, int n_in,
                              void* d_out, int out_size, void* d_ws, size_t ws_size,
                              hipStream_t stream) {
    const float* x  = (const float*)d_in[0];
    const float* cb = (const float*)d_in[1];
    float* out = (float*)d_out;
    char*  ws  = (char*)d_ws;

    unsigned* counts = (unsigned*)(ws + WS_COUNTS);
    double*   sumsq  = (double*)(ws + WS_SUMSQ);
    float*    en2    = (float*)(ws + WS_EN2);
    float*    xn2    = (float*)(ws + WS_XN2);
    int*      idxv   = (int*)(ws + WS_IDX);

    // zero counts (4096 B) + sumsq (8 B) — ws is poisoned 0xAA before each call
    hipMemsetAsync(ws, 0, WS_SUMSQ + 8, stream);

    k_en2<<<K_ / 256, 256, 0, stream>>>(cb, en2);
    k_xn2<<<N_ / 256, 256, 0, stream>>>(x, xn2);
    k_argmin<<<N_ / 64, 256, 0, stream>>>(x, cb, en2, xn2, idxv,
                                          out + IDX_OFF, counts);
    k_gather<<<B_ * H_, 256, 0, stream>>>(x, cb, idxv, out, sumsq);
    k_final<<<1, 256, 0, stream>>>(counts, sumsq, out);
}